// Round 1
// baseline (124.280 us; speedup 1.0000x reference)
//
#include <hip/hip_runtime.h>
#include <math.h>

// Problem constants
#define F_ 126
#define NPG 128              // nodes per graph
#define EPG 2048             // edges per graph
#define ET 524288            // total edges
#define NEG_SLOPE 0.2f
// h layout (type-major): rows [0,32256) features, [32256,32512) users, [32512,32768) items
#define U_BASE 32256
#define I_BASE 32512

typedef short bf16x8 __attribute__((ext_vector_type(8)));
typedef float f32x4 __attribute__((ext_vector_type(4)));

__device__ __forceinline__ float bf2f(unsigned short u) {
  return __uint_as_float(((unsigned)u) << 16);
}
__device__ __forceinline__ unsigned short f2bf(float f) {
  unsigned x = __float_as_uint(f);
  unsigned r = x + 0x7fffu + ((x >> 16) & 1u);   // RNE
  return (unsigned short)(r >> 16);
}
// monotonic float<->uint order map for atomicMax-based segment max
__device__ __forceinline__ unsigned f2ord(float f) {
  unsigned b = __float_as_uint(f);
  return (b & 0x80000000u) ? ~b : (b | 0x80000000u);
}
__device__ __forceinline__ float ord2f(unsigned k) {
  unsigned b = (k & 0x80000000u) ? (k ^ 0x80000000u) : ~k;
  return __uint_as_float(b);
}

// ---------------- K0: WcT[type][c][k] = sum_j W_type[k][j] * W_gat[j][c]  (bf16) ----------
__global__ void k0_wct(const float* __restrict__ Wf, const float* __restrict__ Wu,
                       const float* __restrict__ Wi, const float* __restrict__ Wg,
                       unsigned short* __restrict__ wct) {
  int type = blockIdx.x >> 8;       // 0..2
  int c = blockIdx.x & 255;
  const float* Wx = (type == 0) ? Wf : ((type == 1) ? Wu : Wi);
  __shared__ float gcol[256];
  gcol[threadIdx.x] = Wg[threadIdx.x * 256 + c];
  __syncthreads();
  int k = threadIdx.x;
  const float4* wrow = reinterpret_cast<const float4*>(Wx + k * 256);
  float acc = 0.f;
#pragma unroll 8
  for (int j = 0; j < 64; ++j) {
    float4 v = wrow[j];
    acc += v.x * gcol[4 * j] + v.y * gcol[4 * j + 1] + v.z * gcol[4 * j + 2] + v.w * gcol[4 * j + 3];
  }
  wct[((size_t)type * 256 + c) * 256 + k] = f2bf(acc);
}

// ---------------- K1: h = gathered_embedding @ Wc  (bf16 MFMA, 128x128 tiles) -------------
__global__ __launch_bounds__(512, 4) void k1_h(
    const int* __restrict__ fid, const int* __restrict__ userid, const int* __restrict__ itemid,
    const float* __restrict__ ftab, const float* __restrict__ utab, const float* __restrict__ itab,
    const unsigned short* __restrict__ wct,
    unsigned short* __restrict__ h) {
  __shared__ __align__(16) unsigned short Al[128 * 128];  // 32KB, XOR-swizzled bf16
  __shared__ __align__(16) unsigned short Bl[128 * 128];  // 32KB

  const int bid = blockIdx.x;
  const int tile = bid >> 1;      // 0..255 row tile (252 feat, 2 user, 2 item)
  const int chalf = bid & 1;      // output column half (0/1 -> cols 0..127 / 128..255)
  const int tid = threadIdx.x;

  int type, rowbase;
  if (tile < 252)       { type = 0; rowbase = tile * 128; }
  else if (tile < 254)  { type = 1; rowbase = U_BASE + (tile - 252) * 128; }
  else                  { type = 2; rowbase = I_BASE + (tile - 254) * 128; }

  const int r = tid >> 2;   // 0..127 load row
  const int q = tid & 3;    // quarter of the row
  const float* srcrow;
  if (type == 0)      srcrow = ftab + (size_t)fid[tile * 128 + r] * 256;
  else if (type == 1) srcrow = utab + (size_t)userid[(tile - 252) * 128 + r] * 256;
  else                srcrow = itab + (size_t)itemid[(tile - 254) * 128 + r] * 256;
  const unsigned short* btrow = wct + ((size_t)type * 256 + chalf * 128 + r) * 256;

  const int lane = tid & 63;
  const int wid = tid >> 6;
  const int m0 = (wid & 3) * 32;
  const int n0 = (wid >> 2) * 64;
  const int rl = lane & 15;
  const int kg = lane >> 4;

  f32x4 acc[2][4] = {};
  char* Ab = reinterpret_cast<char*>(Al);
  char* Bb = reinterpret_cast<char*>(Bl);

  for (int kc = 0; kc < 2; ++kc) {
    // stage A chunk: f32 -> bf16, 8B stores, row-XOR swizzle
    {
      const float4* s4 = reinterpret_cast<const float4*>(srcrow + kc * 128 + q * 32);
#pragma unroll
      for (int i = 0; i < 8; ++i) {
        float4 v = s4[i];
        ushort4 b4;
        b4.x = f2bf(v.x); b4.y = f2bf(v.y); b4.z = f2bf(v.z); b4.w = f2bf(v.w);
        int kk = q * 32 + i * 4;
        int bofs = r * 256 + kk * 2;
        bofs ^= (r & 7) << 4;
        *reinterpret_cast<ushort4*>(Ab + bofs) = b4;
      }
      const uint4* bsrc = reinterpret_cast<const uint4*>(btrow + kc * 128 + q * 32);
#pragma unroll
      for (int i = 0; i < 4; ++i) {
        uint4 v = bsrc[i];
        int kk = q * 32 + i * 8;
        int bofs = r * 256 + kk * 2;
        bofs ^= (r & 7) << 4;
        *reinterpret_cast<uint4*>(Bb + bofs) = v;
      }
    }
    __syncthreads();
#pragma unroll
    for (int ks = 0; ks < 4; ++ks) {
      bf16x8 af[2], bfr[4];
#pragma unroll
      for (int mf = 0; mf < 2; ++mf) {
        int row = m0 + mf * 16 + rl;
        int bofs = row * 256 + (ks * 32 + kg * 8) * 2;
        bofs ^= (row & 7) << 4;
        af[mf] = *reinterpret_cast<const bf16x8*>(Ab + bofs);
      }
#pragma unroll
      for (int nf = 0; nf < 4; ++nf) {
        int row = n0 + nf * 16 + rl;
        int bofs = row * 256 + (ks * 32 + kg * 8) * 2;
        bofs ^= (row & 7) << 4;
        bfr[nf] = *reinterpret_cast<const bf16x8*>(Bb + bofs);
      }
#pragma unroll
      for (int mf = 0; mf < 2; ++mf)
#pragma unroll
        for (int nf = 0; nf < 4; ++nf)
          acc[mf][nf] = __builtin_amdgcn_mfma_f32_16x16x32_bf16(af[mf], bfr[nf], acc[mf][nf], 0, 0, 0);
    }
    __syncthreads();
  }
  // store C (bf16): row = (lane>>4)*4 + i, col = lane&15  [verified gfx950 C/D layout]
#pragma unroll
  for (int mf = 0; mf < 2; ++mf) {
#pragma unroll
    for (int nf = 0; nf < 4; ++nf) {
      int col = chalf * 128 + n0 + nf * 16 + rl;
#pragma unroll
      for (int i = 0; i < 4; ++i) {
        int lr = m0 + mf * 16 + (lane >> 4) * 4 + i;
        h[(size_t)(rowbase + lr) * 256 + col] = f2bf(acc[mf][nf][i]);
      }
    }
  }
}

// ---------------- K2: per-graph GAT (softmax over incoming edges) + fused readout ---------
__global__ __launch_bounds__(512) void k2_gat(
    const int* __restrict__ ei,
    const unsigned short* __restrict__ h,
    const float* __restrict__ a_src, const float* __restrict__ a_dst,
    const float* __restrict__ W_out, const float* __restrict__ b_out,
    float* __restrict__ out) {
  const int g = blockIdx.x;
  const int tid = threadIdx.x;
  const int lane = tid & 63;
  const int wid = tid >> 6;

  __shared__ __align__(16) unsigned short hh[128 * 128]; // 32KB: h[:,hp*128:+128] bf16
  __shared__ float as2[128][2], ad2[128][2];
  __shared__ unsigned mkey[128][2];
  __shared__ float mval[128][2];
  __shared__ float denom[128][2];
  __shared__ int cnt[128];
  __shared__ int off_[128];
  __shared__ int fill[128];
  __shared__ unsigned short sorted[2048];                // src local id, CSR by dst
  __shared__ float asl[2][64], adl[2][64];
  __shared__ float wout[256];

  // edges -> registers (4 per thread)
  int4 s4 = *reinterpret_cast<const int4*>(ei + g * EPG + tid * 4);
  int4 d4 = *reinterpret_cast<const int4*>(ei + ET + g * EPG + tid * 4);
  int sl[4] = { s4.x - g * NPG, s4.y - g * NPG, s4.z - g * NPG, s4.w - g * NPG };
  int dl[4] = { d4.x - g * NPG, d4.y - g * NPG, d4.z - g * NPG, d4.w - g * NPG };

  if (tid < 128) cnt[tid] = 0;
  if (tid < 256) wout[tid] = W_out[tid];
  const float bo = b_out[0];
  __syncthreads();

  // histogram by dst
#pragma unroll
  for (int j = 0; j < 4; ++j) atomicAdd(&cnt[dl[j]], 1);
  __syncthreads();

  // wave0: exclusive prefix over 128 bins
  if (wid == 0) {
    int v0 = cnt[lane], v1 = cnt[64 + lane];
    int p0 = v0;
    for (int d = 1; d < 64; d <<= 1) { int t = __shfl_up(p0, d); if (lane >= d) p0 += t; }
    int tot0 = __shfl(p0, 63);
    int p1 = v1;
    for (int d = 1; d < 64; d <<= 1) { int t = __shfl_up(p1, d); if (lane >= d) p1 += t; }
    off_[lane] = p0 - v0;          off_[64 + lane] = tot0 + p1 - v1;
    fill[lane] = p0 - v0;          fill[64 + lane] = tot0 + p1 - v1;
  }
  __syncthreads();

  // scatter into CSR
#pragma unroll
  for (int j = 0; j < 4; ++j) {
    int p = atomicAdd(&fill[dl[j]], 1);
    sorted[p] = (unsigned short)sl[j];
  }

  float lp[16];
#pragma unroll
  for (int j = 0; j < 16; ++j) lp[j] = 0.f;

  for (int hp = 0; hp < 2; ++hp) {
    __syncthreads();  // previous pass fully done with hh / stats
    // stage h half-tile
    {
      int row = tid >> 2, seg = tid & 3;
      int hr = (row < F_) ? (g * F_ + row) : ((row == F_) ? (U_BASE + g) : (I_BASE + g));
      const uint4* src = reinterpret_cast<const uint4*>(h + (size_t)hr * 256 + hp * 128 + seg * 32);
      uint4* dst = reinterpret_cast<uint4*>(hh + row * 128 + seg * 32);
#pragma unroll
      for (int i = 0; i < 4; ++i) dst[i] = src[i];
    }
    if (tid < 128)        asl[tid >> 6][tid & 63] = a_src[hp * 128 + tid];
    else if (tid < 256)   { int u = tid - 128; adl[u >> 6][u & 63] = a_dst[hp * 128 + u]; }
    else                  { int u = tid - 256; mkey[u >> 1][u & 1] = 0u; denom[u >> 1][u & 1] = 0.f; }
    __syncthreads();

    // alpha_src / alpha_dst per (node, local head)
    if (tid < 256) {
      int n = tid >> 1, lh = tid & 1;
      const unsigned short* hrow = hh + n * 128 + lh * 64;
      float a_s = 0.f, a_d = 0.f;
#pragma unroll 8
      for (int d = 0; d < 64; ++d) {
        float hv = bf2f(hrow[d]);
        a_s += hv * asl[lh][d];
        a_d += hv * adl[lh][d];
      }
      as2[n][lh] = a_s;
      ad2[n][lh] = a_d;
    }
    __syncthreads();

    // segment max (ordered-uint atomicMax)
#pragma unroll
    for (int j = 0; j < 4; ++j) {
#pragma unroll
      for (int lh = 0; lh < 2; ++lh) {
        float e = as2[sl[j]][lh] + ad2[dl[j]][lh];
        e = (e < 0.f) ? NEG_SLOPE * e : e;
        atomicMax(&mkey[dl[j]][lh], f2ord(e));
      }
    }
    __syncthreads();
    if (tid < 256) {
      int n = tid >> 1, lh = tid & 1;
      mval[n][lh] = (cnt[n] > 0) ? ord2f(mkey[n][lh]) : 0.f;
    }
    __syncthreads();

    // denom = segment_sum(exp(e - m))
#pragma unroll
    for (int j = 0; j < 4; ++j) {
#pragma unroll
      for (int lh = 0; lh < 2; ++lh) {
        float e = as2[sl[j]][lh] + ad2[dl[j]][lh];
        e = (e < 0.f) ? NEG_SLOPE * e : e;
        atomicAdd(&denom[dl[j]][lh], __expf(e - mval[dl[j]][lh]));
      }
    }
    __syncthreads();

    // aggregation: wave per dst node, lane owns 2 dims of the 128-half
    const int d0 = lane * 2;
    const int lh = lane >> 5;
#pragma unroll
    for (int jn = 0; jn < 16; ++jn) {
      int n = wid + jn * 8;
      if (n < F_) {
        int deg = cnt[n];
        float a0 = 0.f, a1 = 0.f;
        if (deg > 0) {
          int o = off_[n];
          float mv = mval[n][lh];
          float rd = 1.f / (denom[n][lh] + 1e-16f);
          float adv = ad2[n][lh];
          int k = 0;
          for (; k + 2 <= deg; k += 2) {
            int sA = sorted[o + k], sB = sorted[o + k + 1];
            float eA = as2[sA][lh] + adv; eA = (eA < 0.f) ? NEG_SLOPE * eA : eA;
            float eB = as2[sB][lh] + adv; eB = (eB < 0.f) ? NEG_SLOPE * eB : eB;
            float alA = __expf(eA - mv) * rd;
            float alB = __expf(eB - mv) * rd;
            unsigned hA = *reinterpret_cast<const unsigned*>(hh + sA * 128 + d0);
            unsigned hB = *reinterpret_cast<const unsigned*>(hh + sB * 128 + d0);
            a0 += alA * bf2f((unsigned short)(hA & 0xffffu));
            a1 += alA * bf2f((unsigned short)(hA >> 16));
            a0 += alB * bf2f((unsigned short)(hB & 0xffffu));
            a1 += alB * bf2f((unsigned short)(hB >> 16));
          }
          if (k < deg) {
            int sA = sorted[o + k];
            float eA = as2[sA][lh] + adv; eA = (eA < 0.f) ? NEG_SLOPE * eA : eA;
            float alA = __expf(eA - mv) * rd;
            unsigned hA = *reinterpret_cast<const unsigned*>(hh + sA * 128 + d0);
            a0 += alA * bf2f((unsigned short)(hA & 0xffffu));
            a1 += alA * bf2f((unsigned short)(hA >> 16));
          }
        }
        float h0 = (a0 > 0.f) ? a0 : expm1f(a0);   // ELU
        float h1 = (a1 > 0.f) ? a1 : expm1f(a1);
        lp[jn] += h0 * wout[hp * 128 + d0] + h1 * wout[hp * 128 + d0 + 1];
      }
    }
  }

  // reduce readout partials and write logits
#pragma unroll
  for (int jn = 0; jn < 16; ++jn) {
    int n = wid + jn * 8;
    if (n < F_) {
      float v = lp[jn];
      for (int d = 32; d >= 1; d >>= 1) v += __shfl_xor(v, d);
      if (lane == 0) out[g * F_ + n] = v + bo;
    }
  }
}

extern "C" void kernel_launch(void* const* d_in, const int* in_sizes, int n_in,
                              void* d_out, int out_size, void* d_ws, size_t ws_size,
                              hipStream_t stream) {
  const int* fid      = (const int*)d_in[0];
  const int* userid   = (const int*)d_in[1];
  const int* itemid   = (const int*)d_in[2];
  const int* ei       = (const int*)d_in[3];
  const float* ftab   = (const float*)d_in[4];
  const float* utab   = (const float*)d_in[5];
  const float* itab   = (const float*)d_in[6];
  const float* Wf     = (const float*)d_in[7];
  const float* Wu     = (const float*)d_in[8];
  const float* Wi     = (const float*)d_in[9];
  const float* Wg     = (const float*)d_in[10];
  const float* a_src  = (const float*)d_in[11];
  const float* a_dst  = (const float*)d_in[12];
  const float* W_out  = (const float*)d_in[13];
  const float* b_out  = (const float*)d_in[14];
  float* out = (float*)d_out;

  // workspace: h bf16 [32768][256] (16 MB) + WcT bf16 3*[256][256] (384 KB)
  unsigned short* ws_h   = (unsigned short*)d_ws;
  unsigned short* ws_wct = ws_h + (size_t)32768 * 256;

  hipLaunchKernelGGL(k0_wct, dim3(768), dim3(256), 0, stream, Wf, Wu, Wi, Wg, ws_wct);
  hipLaunchKernelGGL(k1_h, dim3(512), dim3(512), 0, stream,
                     fid, userid, itemid, ftab, utab, itab, ws_wct, ws_h);
  hipLaunchKernelGGL(k2_gat, dim3(256), dim3(512), 0, stream,
                     ei, ws_h, a_src, a_dst, W_out, b_out, out);
}

// Round 2
// 118.276 us; speedup vs baseline: 1.0508x; 1.0508x over previous
//
#include <hip/hip_runtime.h>
#include <math.h>

// Problem constants
#define F_ 126
#define NPG 128              // nodes per graph
#define EPG 2048             // edges per graph
#define ET 524288            // total edges
#define NEG_SLOPE 0.2f
// h layout (type-major): rows [0,32256) features, [32256,32512) users, [32512,32768) items
#define U_BASE 32256
#define I_BASE 32512

typedef short bf16x8 __attribute__((ext_vector_type(8)));
typedef float f32x4 __attribute__((ext_vector_type(4)));

__device__ __forceinline__ float bf2f(unsigned short u) {
  return __uint_as_float(((unsigned)u) << 16);
}
__device__ __forceinline__ unsigned short f2bf(float f) {
  unsigned x = __float_as_uint(f);
  unsigned r = x + 0x7fffu + ((x >> 16) & 1u);   // RNE
  return (unsigned short)(r >> 16);
}
// monotonic float<->uint order map for atomicMax-based segment max
__device__ __forceinline__ unsigned f2ord(float f) {
  unsigned b = __float_as_uint(f);
  return (b & 0x80000000u) ? ~b : (b | 0x80000000u);
}
__device__ __forceinline__ float ord2f(unsigned k) {
  unsigned b = (k & 0x80000000u) ? (k ^ 0x80000000u) : ~k;
  return __uint_as_float(b);
}

// ---------------- K0: WcT[type][c][k] = sum_j W_type[k][j] * W_gat[j][c]  (bf16) ----------
__global__ void k0_wct(const float* __restrict__ Wf, const float* __restrict__ Wu,
                       const float* __restrict__ Wi, const float* __restrict__ Wg,
                       unsigned short* __restrict__ wct) {
  int type = blockIdx.x >> 8;       // 0..2
  int c = blockIdx.x & 255;
  const float* Wx = (type == 0) ? Wf : ((type == 1) ? Wu : Wi);
  __shared__ float gcol[256];
  gcol[threadIdx.x] = Wg[threadIdx.x * 256 + c];
  __syncthreads();
  int k = threadIdx.x;
  const float4* wrow = reinterpret_cast<const float4*>(Wx + k * 256);
  float acc = 0.f;
#pragma unroll 8
  for (int j = 0; j < 64; ++j) {
    float4 v = wrow[j];
    acc += v.x * gcol[4 * j] + v.y * gcol[4 * j + 1] + v.z * gcol[4 * j + 2] + v.w * gcol[4 * j + 3];
  }
  wct[((size_t)type * 256 + c) * 256 + k] = f2bf(acc);
}

// ---------------- K1: h = gathered_embedding @ Wc  (bf16 MFMA, 128x128 tiles) -------------
__global__ __launch_bounds__(512, 4) void k1_h(
    const int* __restrict__ fid, const int* __restrict__ userid, const int* __restrict__ itemid,
    const float* __restrict__ ftab, const float* __restrict__ utab, const float* __restrict__ itab,
    const unsigned short* __restrict__ wct,
    unsigned short* __restrict__ h) {
  __shared__ __align__(16) unsigned short Al[128 * 128];  // 32KB, XOR-swizzled bf16
  __shared__ __align__(16) unsigned short Bl[128 * 128];  // 32KB

  const int bid = blockIdx.x;
  const int tile = bid >> 1;      // 0..255 row tile (252 feat, 2 user, 2 item)
  const int chalf = bid & 1;      // output column half (0/1 -> cols 0..127 / 128..255)
  const int tid = threadIdx.x;

  int type, rowbase;
  if (tile < 252)       { type = 0; rowbase = tile * 128; }
  else if (tile < 254)  { type = 1; rowbase = U_BASE + (tile - 252) * 128; }
  else                  { type = 2; rowbase = I_BASE + (tile - 254) * 128; }

  const int r = tid >> 2;   // 0..127 load row
  const int q = tid & 3;    // quarter of the row
  const float* srcrow;
  if (type == 0)      srcrow = ftab + (size_t)fid[tile * 128 + r] * 256;
  else if (type == 1) srcrow = utab + (size_t)userid[(tile - 252) * 128 + r] * 256;
  else                srcrow = itab + (size_t)itemid[(tile - 254) * 128 + r] * 256;
  const unsigned short* btrow = wct + ((size_t)type * 256 + chalf * 128 + r) * 256;

  const int lane = tid & 63;
  const int wid = tid >> 6;
  const int m0 = (wid & 3) * 32;
  const int n0 = (wid >> 2) * 64;
  const int rl = lane & 15;
  const int kg = lane >> 4;

  f32x4 acc[2][4] = {};
  char* Ab = reinterpret_cast<char*>(Al);
  char* Bb = reinterpret_cast<char*>(Bl);

  for (int kc = 0; kc < 2; ++kc) {
    // stage A chunk: f32 -> bf16, 8B stores, row-XOR swizzle
    {
      const float4* s4 = reinterpret_cast<const float4*>(srcrow + kc * 128 + q * 32);
#pragma unroll
      for (int i = 0; i < 8; ++i) {
        float4 v = s4[i];
        ushort4 b4;
        b4.x = f2bf(v.x); b4.y = f2bf(v.y); b4.z = f2bf(v.z); b4.w = f2bf(v.w);
        int kk = q * 32 + i * 4;
        int bofs = r * 256 + kk * 2;
        bofs ^= (r & 7) << 4;
        *reinterpret_cast<ushort4*>(Ab + bofs) = b4;
      }
      const uint4* bsrc = reinterpret_cast<const uint4*>(btrow + kc * 128 + q * 32);
#pragma unroll
      for (int i = 0; i < 4; ++i) {
        uint4 v = bsrc[i];
        int kk = q * 32 + i * 8;
        int bofs = r * 256 + kk * 2;
        bofs ^= (r & 7) << 4;
        *reinterpret_cast<uint4*>(Bb + bofs) = v;
      }
    }
    __syncthreads();
#pragma unroll
    for (int ks = 0; ks < 4; ++ks) {
      bf16x8 af[2], bfr[4];
#pragma unroll
      for (int mf = 0; mf < 2; ++mf) {
        int row = m0 + mf * 16 + rl;
        int bofs = row * 256 + (ks * 32 + kg * 8) * 2;
        bofs ^= (row & 7) << 4;
        af[mf] = *reinterpret_cast<const bf16x8*>(Ab + bofs);
      }
#pragma unroll
      for (int nf = 0; nf < 4; ++nf) {
        int row = n0 + nf * 16 + rl;
        int bofs = row * 256 + (ks * 32 + kg * 8) * 2;
        bofs ^= (row & 7) << 4;
        bfr[nf] = *reinterpret_cast<const bf16x8*>(Bb + bofs);
      }
#pragma unroll
      for (int mf = 0; mf < 2; ++mf)
#pragma unroll
        for (int nf = 0; nf < 4; ++nf)
          acc[mf][nf] = __builtin_amdgcn_mfma_f32_16x16x32_bf16(af[mf], bfr[nf], acc[mf][nf], 0, 0, 0);
    }
    __syncthreads();
  }
  // store C (bf16): row = (lane>>4)*4 + i, col = lane&15  [verified gfx950 C/D layout]
#pragma unroll
  for (int mf = 0; mf < 2; ++mf) {
#pragma unroll
    for (int nf = 0; nf < 4; ++nf) {
      int col = chalf * 128 + n0 + nf * 16 + rl;
#pragma unroll
      for (int i = 0; i < 4; ++i) {
        int lr = m0 + mf * 16 + (lane >> 4) * 4 + i;
        h[(size_t)(rowbase + lr) * 256 + col] = f2bf(acc[mf][nf][i]);
      }
    }
  }
}

// ---------------- K2: per-graph GAT + fused readout ---------------------------------------
// grid = 512: block (g, nh) handles graph g, dst-node half nh (nodes nh*64 .. nh*64+63).
// Setup (CSR, alpha, per-edge weights) duplicated across the two blocks of a graph; outputs
// disjoint so no cross-block reduction needed.
__global__ __launch_bounds__(512) void k2_gat(
    const int* __restrict__ ei,
    const unsigned short* __restrict__ h,
    const float* __restrict__ a_src, const float* __restrict__ a_dst,
    const float* __restrict__ W_out, const float* __restrict__ b_out,
    float* __restrict__ out) {
  const int g = blockIdx.x >> 1;
  const int nh = blockIdx.x & 1;
  const int tid = threadIdx.x;
  const int lane = tid & 63;
  const int wid = tid >> 6;

  __shared__ __align__(16) unsigned short hh[128 * 128]; // 32KB, XOR-swizzled (row&7)<<4
  __shared__ float wcsr[2048 * 2];                       // 16KB: per-edge exp(e-m), CSR order
  __shared__ float as2[128][2], ad2[128][2];
  __shared__ unsigned mkey[128 * 2];
  __shared__ float mval[128][2];
  __shared__ float denom[128][2];
  __shared__ int cnt[128];
  __shared__ int off_[128];
  __shared__ int fill[128];
  __shared__ unsigned short sorted[2048];                // src local id, CSR by dst
  __shared__ float asl[128], adl[128];                   // a_src/a_dst for current 128-dim half
  __shared__ float wout[256];

  char* Hb = reinterpret_cast<char*>(hh);

  // edges -> registers (4 per thread)
  int4 s4 = *reinterpret_cast<const int4*>(ei + g * EPG + tid * 4);
  int4 d4 = *reinterpret_cast<const int4*>(ei + ET + g * EPG + tid * 4);
  int sl[4] = { s4.x - g * NPG, s4.y - g * NPG, s4.z - g * NPG, s4.w - g * NPG };
  int dl[4] = { d4.x - g * NPG, d4.y - g * NPG, d4.z - g * NPG, d4.w - g * NPG };

  if (tid < 128) cnt[tid] = 0;
  if (tid < 256) wout[tid] = W_out[tid];
  const float bo = b_out[0];
  __syncthreads();

  // histogram by dst
#pragma unroll
  for (int j = 0; j < 4; ++j) atomicAdd(&cnt[dl[j]], 1);
  __syncthreads();

  // wave0: exclusive prefix over 128 bins
  if (wid == 0) {
    int v0 = cnt[lane], v1 = cnt[64 + lane];
    int p0 = v0;
    for (int d = 1; d < 64; d <<= 1) { int t = __shfl_up(p0, d); if (lane >= d) p0 += t; }
    int tot0 = __shfl(p0, 63);
    int p1 = v1;
    for (int d = 1; d < 64; d <<= 1) { int t = __shfl_up(p1, d); if (lane >= d) p1 += t; }
    off_[lane] = p0 - v0;          off_[64 + lane] = tot0 + p1 - v1;
    fill[lane] = p0 - v0;          fill[64 + lane] = tot0 + p1 - v1;
  }
  __syncthreads();

  // scatter into CSR; remember each edge's slot for the weight write later
  int p[4];
#pragma unroll
  for (int j = 0; j < 4; ++j) {
    p[j] = atomicAdd(&fill[dl[j]], 1);
    sorted[p[j]] = (unsigned short)sl[j];
  }

  float lp[8];
#pragma unroll
  for (int j = 0; j < 8; ++j) lp[j] = 0.f;

  for (int hp = 0; hp < 2; ++hp) {
    __syncthreads();  // previous pass fully done with hh / wcsr / stats
    // stage h half-tile (16B stores, XOR swizzle)
    {
      int row = tid >> 2, seg = tid & 3;
      int hr = (row < F_) ? (g * F_ + row) : ((row == F_) ? (U_BASE + g) : (I_BASE + g));
      const uint4* src = reinterpret_cast<const uint4*>(h + (size_t)hr * 256 + hp * 128 + seg * 32);
#pragma unroll
      for (int i = 0; i < 4; ++i) {
        int bofs = row * 256 + seg * 64 + i * 16;
        bofs ^= (row & 7) << 4;
        *reinterpret_cast<uint4*>(Hb + bofs) = src[i];
      }
    }
    if (tid < 128)        asl[tid] = a_src[hp * 128 + tid];
    else if (tid < 256)   adl[tid - 128] = a_dst[hp * 128 + tid - 128];
    else if (tid < 512) { int u = tid - 256; mkey[u] = 0u; reinterpret_cast<float*>(denom)[u] = 0.f; }
    __syncthreads();

    // alpha_src/alpha_dst: wave-cooperative. lane -> node n = wid*16+(lane&15), chunk c=lane>>4
    {
      int n = wid * 16 + (lane & 15);
      int c = lane >> 4;
      float a_s = 0.f, a_d = 0.f;
#pragma unroll
      for (int i = 0; i < 4; ++i) {
        int bofs = n * 256 + c * 64 + i * 16;
        bofs ^= (n & 7) << 4;
        bf16x8 v = *reinterpret_cast<const bf16x8*>(Hb + bofs);
#pragma unroll
        for (int jj = 0; jj < 8; ++jj) {
          int d = c * 32 + i * 8 + jj;
          float hv = bf2f((unsigned short)v[jj]);
          a_s += hv * asl[d];
          a_d += hv * adl[d];
        }
      }
      a_s += __shfl_xor(a_s, 16);     // c0+c1 (head0), c2+c3 (head1)
      a_d += __shfl_xor(a_d, 16);
      if (c == 0)      { as2[n][0] = a_s; ad2[n][0] = a_d; }
      else if (c == 2) { as2[n][1] = a_s; ad2[n][1] = a_d; }
    }
    __syncthreads();

    // segment max (ordered-uint atomicMax)
#pragma unroll
    for (int j = 0; j < 4; ++j) {
#pragma unroll
      for (int lh = 0; lh < 2; ++lh) {
        float e = as2[sl[j]][lh] + ad2[dl[j]][lh];
        e = (e < 0.f) ? NEG_SLOPE * e : e;
        atomicMax(&mkey[dl[j] * 2 + lh], f2ord(e));
      }
    }
    __syncthreads();
    if (tid < 256) {
      int n = tid >> 1, lh = tid & 1;
      mval[n][lh] = (cnt[n] > 0) ? ord2f(mkey[n * 2 + lh]) : 0.f;
    }
    __syncthreads();

    // per-edge weight ee = exp(e - m) -> CSR slot; accumulate denom
#pragma unroll
    for (int j = 0; j < 4; ++j) {
#pragma unroll
      for (int lh = 0; lh < 2; ++lh) {
        float e = as2[sl[j]][lh] + ad2[dl[j]][lh];
        e = (e < 0.f) ? NEG_SLOPE * e : e;
        float ee = __expf(e - mval[dl[j]][lh]);
        wcsr[p[j] * 2 + lh] = ee;
        atomicAdd(&denom[dl[j]][lh], ee);
      }
    }
    __syncthreads();

    // aggregation: wave per dst node (this block's half), lane owns 2 dims of the 128-half
    const int d0 = lane * 2;
    const int lh = lane >> 5;
#pragma unroll
    for (int jn = 0; jn < 8; ++jn) {
      int n = nh * 64 + jn * 8 + wid;
      if (n < F_) {
        int deg = cnt[n];
        float a0 = 0.f, a1 = 0.f;
        if (deg > 0) {
          int o = off_[n];
          float rd = 1.f / (denom[n][lh] + 1e-16f);
          int k = 0;
          for (; k + 4 <= deg; k += 4) {
            int sA = sorted[o + k],     sB = sorted[o + k + 1];
            int sC = sorted[o + k + 2], sD = sorted[o + k + 3];
            float wA = wcsr[(o + k) * 2 + lh],     wB = wcsr[(o + k + 1) * 2 + lh];
            float wC = wcsr[(o + k + 2) * 2 + lh], wD = wcsr[(o + k + 3) * 2 + lh];
            unsigned hA = *reinterpret_cast<const unsigned*>(Hb + ((sA * 256 + d0 * 2) ^ ((sA & 7) << 4)));
            unsigned hB = *reinterpret_cast<const unsigned*>(Hb + ((sB * 256 + d0 * 2) ^ ((sB & 7) << 4)));
            unsigned hC = *reinterpret_cast<const unsigned*>(Hb + ((sC * 256 + d0 * 2) ^ ((sC & 7) << 4)));
            unsigned hD = *reinterpret_cast<const unsigned*>(Hb + ((sD * 256 + d0 * 2) ^ ((sD & 7) << 4)));
            a0 += wA * __uint_as_float(hA << 16); a1 += wA * __uint_as_float(hA & 0xffff0000u);
            a0 += wB * __uint_as_float(hB << 16); a1 += wB * __uint_as_float(hB & 0xffff0000u);
            a0 += wC * __uint_as_float(hC << 16); a1 += wC * __uint_as_float(hC & 0xffff0000u);
            a0 += wD * __uint_as_float(hD << 16); a1 += wD * __uint_as_float(hD & 0xffff0000u);
          }
          for (; k < deg; ++k) {
            int sA = sorted[o + k];
            float wA = wcsr[(o + k) * 2 + lh];
            unsigned hA = *reinterpret_cast<const unsigned*>(Hb + ((sA * 256 + d0 * 2) ^ ((sA & 7) << 4)));
            a0 += wA * __uint_as_float(hA << 16); a1 += wA * __uint_as_float(hA & 0xffff0000u);
          }
          a0 *= rd; a1 *= rd;
        }
        float h0 = (a0 > 0.f) ? a0 : expm1f(a0);   // ELU
        float h1 = (a1 > 0.f) ? a1 : expm1f(a1);
        lp[jn] += h0 * wout[hp * 128 + d0] + h1 * wout[hp * 128 + d0 + 1];
      }
    }
  }

  // reduce readout partials and write logits
#pragma unroll
  for (int jn = 0; jn < 8; ++jn) {
    int n = nh * 64 + jn * 8 + wid;
    if (n < F_) {
      float v = lp[jn];
      for (int d = 32; d >= 1; d >>= 1) v += __shfl_xor(v, d);
      if (lane == 0) out[g * F_ + n] = v + bo;
    }
  }
}

extern "C" void kernel_launch(void* const* d_in, const int* in_sizes, int n_in,
                              void* d_out, int out_size, void* d_ws, size_t ws_size,
                              hipStream_t stream) {
  const int* fid      = (const int*)d_in[0];
  const int* userid   = (const int*)d_in[1];
  const int* itemid   = (const int*)d_in[2];
  const int* ei       = (const int*)d_in[3];
  const float* ftab   = (const float*)d_in[4];
  const float* utab   = (const float*)d_in[5];
  const float* itab   = (const float*)d_in[6];
  const float* Wf     = (const float*)d_in[7];
  const float* Wu     = (const float*)d_in[8];
  const float* Wi     = (const float*)d_in[9];
  const float* Wg     = (const float*)d_in[10];
  const float* a_src  = (const float*)d_in[11];
  const float* a_dst  = (const float*)d_in[12];
  const float* W_out  = (const float*)d_in[13];
  const float* b_out  = (const float*)d_in[14];
  float* out = (float*)d_out;

  // workspace: h bf16 [32768][256] (16 MB) + WcT bf16 3*[256][256] (384 KB)
  unsigned short* ws_h   = (unsigned short*)d_ws;
  unsigned short* ws_wct = ws_h + (size_t)32768 * 256;

  hipLaunchKernelGGL(k0_wct, dim3(768), dim3(256), 0, stream, Wf, Wu, Wi, Wg, ws_wct);
  hipLaunchKernelGGL(k1_h, dim3(512), dim3(512), 0, stream,
                     fid, userid, itemid, ftab, utab, itab, ws_wct, ws_h);
  hipLaunchKernelGGL(k2_gat, dim3(512), dim3(512), 0, stream,
                     ei, ws_h, a_src, a_dst, W_out, b_out, out);
}